// Round 17
// baseline (97.814 us; speedup 1.0000x reference)
//
#include <hip/hip_runtime.h>

#define VOCABN 256
#define DN 512
#define DSN 2
#define KN 5
#define BN 8
#define LN 8192
#define WN 12
#define NW12 ((LN + WN - 1) / WN)  // 683 windows per batch
#define NWIN (BN * NW12)           // 5464
#define LOUTN (LN / DSN)           // 4096
#define NROWS (KN * VOCABN)        // 1280
#define ROWB (DN * 2)              // 1024 B per bf16 G row
#define SBIAS_IDX (NROWS + 4 * VOCABN + 1)  // 2305 (layout kept from r11)
#define ISP 4
#define NSLICE 8
#define SCH 64                     // channels per slice
#define NGRP 32
#define WPG ((NWIN + NGRP - 1) / NGRP)  // 171

// Workspace (BYTES):
//   Gp   : 10,485,760 @ 0
//   G    :  2,360,320 @ 10,485,760
//   SW   :      9,224 @ 12,846,080
//   COEF : 8*8192*16 = 1,048,576*2 @ 12,855,552 (16B aligned)
#define GP_BYTES ((size_t)ISP * NROWS * DN * 4)
#define G_OFF GP_BYTES
#define SW_OFF (G_OFF + (size_t)2305 * ROWB)
#define COEF_OFF ((size_t)12855552)

__device__ inline unsigned short f2bf(float f) {  // RNE f32->bf16
  unsigned int x = __float_as_uint(f);
  return (unsigned short)((x + 0x7FFFu + ((x >> 16) & 1u)) >> 16);
}

// ---------------- kernel 1: build GEMM partials (round-7/11 verbatim) ----------------
__global__ __launch_bounds__(256) void gbuild_kernel(const float* __restrict__ emb,
                                                     const float* __restrict__ cw,
                                                     float* __restrict__ Gp) {
  const int bx = blockIdx.x;
  const int vt = bx & 3, ot = (bx >> 2) & 7;
  const int kq = bx >> 5;
  const int k = kq % 5, isp = kq / 5;
  const int v0 = vt * 64, o0 = ot * 64;
  const int tid = threadIdx.x;
  const int ox = tid & 15, vx = tid >> 4;
  const int c = tid & 31, rr = tid >> 5;
  __shared__ float se[32][68];
  __shared__ float wt[32][68];
  float acc[4][4] = {};
  for (int ic = 0; ic < 4; ++ic) {
    const int i0 = isp * 128 + ic * 32;
    __syncthreads();
#pragma unroll
    for (int p = 0; p < 8; ++p) {
      const int q = p * 8 + rr;
      se[c][q] = emb[(size_t)(v0 + q) * DN + i0 + c];
      wt[c][q] = cw[((size_t)(o0 + q) * DN + i0 + c) * KN + k];
    }
    __syncthreads();
#pragma unroll
    for (int i = 0; i < 32; ++i) {
      const float4 a = *(const float4*)&se[i][vx * 4];
      const float4 b = *(const float4*)&wt[i][ox * 4];
      acc[0][0] += a.x * b.x; acc[0][1] += a.x * b.y; acc[0][2] += a.x * b.z; acc[0][3] += a.x * b.w;
      acc[1][0] += a.y * b.x; acc[1][1] += a.y * b.y; acc[1][2] += a.y * b.z; acc[1][3] += a.y * b.w;
      acc[2][0] += a.z * b.x; acc[2][1] += a.z * b.y; acc[2][2] += a.z * b.z; acc[2][3] += a.z * b.w;
      acc[3][0] += a.w * b.x; acc[3][1] += a.w * b.y; acc[3][2] += a.w * b.z; acc[3][3] += a.w * b.w;
    }
  }
#pragma unroll
  for (int vi = 0; vi < 4; ++vi) {
    const int row = k * VOCABN + v0 + vx * 4 + vi;
    float4 f;
    f.x = acc[vi][0]; f.y = acc[vi][1]; f.z = acc[vi][2]; f.w = acc[vi][3];
    *(float4*)(Gp + ((size_t)isp * NROWS + row) * DN + o0 + ox * 4) = f;
  }
}

// ---------------- kernel 2: merged reduce + score table (round-11 verbatim) ----------------
__global__ __launch_bounds__(256) void gswr_kernel(const float* __restrict__ Gp,
                                                   const float* __restrict__ conv_b,
                                                   const float* __restrict__ score_w,
                                                   unsigned int* __restrict__ G32,
                                                   float* __restrict__ SW) {
  const int r = blockIdx.x;
  const int tid = threadIdx.x;
  __shared__ float sred[4];
  if (r >= NROWS && r < NROWS + 5) {
    const int z = NROWS + (r - NROWS) * VOCABN;
    G32[(size_t)z * 256 + tid] = 0u;
    if (tid == 0) SW[z] = 0.f;
    return;
  }
  const float2 sw2 = *(const float2*)(score_w + tid * 2);
  float sdot;
  if (r == NROWS + 5) {
    const float2 cb2 = *(const float2*)(conv_b + tid * 2);
    sdot = cb2.x * sw2.x + cb2.y * sw2.y;
  } else {
    float x = 0.f, y = 0.f;
#pragma unroll
    for (int isp = 0; isp < ISP; ++isp) {
      const float2 p = *(const float2*)(Gp + ((size_t)isp * NROWS + r) * DN + tid * 2);
      x += p.x;
      y += p.y;
    }
    G32[(size_t)r * 256 + tid] = (unsigned)f2bf(x) | ((unsigned)f2bf(y) << 16);
    sdot = x * sw2.x + y * sw2.y;
  }
#pragma unroll
  for (int off = 32; off > 0; off >>= 1) sdot += __shfl_xor(sdot, off, 64);
  if ((tid & 63) == 0) sred[tid >> 6] = sdot;
  __syncthreads();
  if (tid == 0) {
    const float v = sred[0] + sred[1] + sred[2] + sred[3];
    if (r == NROWS + 5) SW[SBIAS_IDX] = v;
    else SW[r] = v;
  }
}

// ---------------- kernel 3: per-position softmax coefficients ----------------
// grid 256 = 8 batches x 32 chunks of 256 positions; thread <-> position.
// coefs[b*LN+p] = {c1,c2,c3,c4} premultiplied with pool norms and final 0.5.
// t(q)=0 for q outside [0,LN). id=0 rows have SW=0 (emb[0]=0), so no tap masking.
__global__ __launch_bounds__(256) void coef_kernel(const int* __restrict__ ids,
                                                   const float* __restrict__ SW,
                                                   float4* __restrict__ coefs) {
  const int bx = blockIdx.x;
  const int b = bx >> 5;
  const int p0 = (bx & 31) * 256;
  const int tid = threadIdx.x;
  __shared__ float tsh[262];  // t for positions p0-3 .. p0+258
  const float sbias = SW[SBIAS_IDX];
  for (int u = tid; u < 262; u += 256) {
    const int q = p0 - 3 + u;
    float tv = 0.f;
    if ((unsigned)q < (unsigned)LN) {
      tv = sbias;
#pragma unroll
      for (int kk = 0; kk < KN; ++kk) {
        const int pp = q + kk - 2;
        const int id = ((unsigned)pp < (unsigned)LN) ? ids[b * LN + pp] : 0;
        tv += SW[kk * VOCABN + id];
      }
    }
    tsh[u] = tv;
  }
  __syncthreads();
  const int p = p0 + tid;
  const int base = p0 - 3;
  const float s1 = tsh[p - base];
  const int j2 = p & ~1;
  const float s2 = 0.5f * (tsh[j2 - base] + tsh[j2 + 1 - base]);
  const int j3 = (p / 3) * 3;
  const float s3 = (1.f / 3.f) * (tsh[j3 - base] + tsh[j3 + 1 - base] + tsh[j3 + 2 - base]);
  const int j4 = p & ~3;
  const float s4 =
      0.25f * (tsh[j4 - base] + tsh[j4 + 1 - base] + tsh[j4 + 2 - base] + tsh[j4 + 3 - base]);
  const float mx = fmaxf(fmaxf(s1, s2), fmaxf(s3, s4));
  const float e1 = __expf(s1 - mx), e2 = __expf(s2 - mx);
  const float e3 = __expf(s3 - mx), e4 = __expf(s4 - mx);
  const float inv = 0.5f / (e1 + e2 + e3 + e4);  // folds the final /2 downsample
  float4 cf;
  cf.x = e1 * inv;
  cf.y = e2 * inv * 0.5f;
  cf.z = e3 * inv * (1.f / 3.f);
  cf.w = e4 * inv * 0.25f;
  coefs[(size_t)b * LN + p] = cf;
}

// ---------------- kernel 4: fused GBST main — LDS-resident G slice ----------------
// grid 256 = 8 slices x 32 window-groups; 512 thr; 1 block/CU (160 KB LDS).
// Block stages its 64-channel slice of G once; each wave then serves ~21 windows
// entirely from LDS. Lane <-> channel; invalid taps use id 0 (G row 0 is all-zero).
__global__ __launch_bounds__(512, 1) void gbst_main_kernel(const int* __restrict__ ids,
                                                           const unsigned short* __restrict__ G,
                                                           const float4* __restrict__ coefs,
                                                           const float* __restrict__ conv_b,
                                                           float* __restrict__ out) {
  __shared__ unsigned short gs[NROWS * SCH];  // 163,840 B = full LDS
  const int bx = blockIdx.x;
  const int slice = bx & 7;
  const int grp = bx >> 3;
  const int tid = threadIdx.x;
  const int ln = tid & 63;
  const int wv = tid >> 6;

  // stage slice: 20 passes x (8 waves x 8 rows), uint4 per lane
  const char* Gb = (const char*)G + slice * (SCH * 2);
#pragma unroll 4
  for (int pass = 0; pass < 20; ++pass) {
    const int r = pass * 64 + wv * 8 + (ln >> 3);
    const uint4 d = *(const uint4*)(Gb + (size_t)r * ROWB + (ln & 7) * 16);
    *(uint4*)((char*)gs + (size_t)r * (SCH * 2) + (ln & 7) * 16) = d;
  }
  __syncthreads();

  const float bias = conv_b[slice * SCH + ln];

  for (int u = wv; u < WPG; u += 8) {
    const int win0 = grp * WPG + u;
    if (win0 >= NWIN) break;
    const int win = __builtin_amdgcn_readfirstlane(win0);
    const int b = win / NW12;
    const int ww = win - b * NW12;
    const int l0 = ww * WN;

    // tap ids (wave-uniform scalars); id 0 for out-of-range (zero G row)
    int idv[WN + 4];
#pragma unroll
    for (int j = 0; j < WN + 4; ++j) {
      const int p = l0 + j - 2;
      const bool tv = ((unsigned)p < (unsigned)LN);
      idv[j] = tv ? __builtin_amdgcn_readfirstlane(ids[b * LN + (tv ? p : 0)]) : 0;
    }

    // y from LDS
    float y[WN];
#pragma unroll
    for (int s = 0; s < WN; ++s) {
      if (l0 + s < LN) {
        float acc = bias;
#pragma unroll
        for (int kk = 0; kk < KN; ++kk) {
          const unsigned v = gs[(kk * VOCABN + idv[s + kk]) * SCH + ln];
          acc += __uint_as_float(v << 16);
        }
        y[s] = acc;
      } else {
        y[s] = 0.f;
      }
    }

    // pool sums
    float S2[6], S3[4], S4[3];
#pragma unroll
    for (int j = 0; j < 6; ++j) S2[j] = y[2 * j] + y[2 * j + 1];
#pragma unroll
    for (int j = 0; j < 4; ++j) S3[j] = y[3 * j] + y[3 * j + 1] + y[3 * j + 2];
#pragma unroll
    for (int j = 0; j < 3; ++j) S4[j] = S2[2 * j] + S2[2 * j + 1];

    // epilogue with precomputed coefficients
#pragma unroll
    for (int jo = 0; jo < WN / 2; ++jo) {
      const int orow = (l0 >> 1) + jo;
      if (orow < LOUTN) {
        float a = 0.f;
#pragma unroll
        for (int dl = 0; dl < 2; ++dl) {
          const int ll = 2 * jo + dl;
          if (l0 + ll < LN) {
            const float4 cf = coefs[(size_t)b * LN + l0 + ll];
            a += cf.x * y[ll] + cf.y * S2[jo] + cf.z * S3[ll / 3] + cf.w * S4[jo >> 1];
          }
        }
        out[((size_t)b * LOUTN + orow) * DN + slice * SCH + ln] = a;
      }
    }
  }
}

extern "C" void kernel_launch(void* const* d_in, const int* in_sizes, int n_in,
                              void* d_out, int out_size, void* d_ws, size_t ws_size,
                              hipStream_t stream) {
  const int* ids = (const int*)d_in[0];
  const float* emb = (const float*)d_in[1];
  const float* conv_w = (const float*)d_in[2];
  const float* conv_b = (const float*)d_in[3];
  const float* score_w = (const float*)d_in[4];
  float* out = (float*)d_out;

  char* ws = (char*)d_ws;
  float* Gp = (float*)ws;
  unsigned short* G = (unsigned short*)(ws + G_OFF);
  float* SW = (float*)(ws + SW_OFF);
  float4* coefs = (float4*)(ws + COEF_OFF);

  gbuild_kernel<<<dim3(640), dim3(256), 0, stream>>>(emb, conv_w, Gp);
  gswr_kernel<<<dim3(NROWS + 6), dim3(256), 0, stream>>>(Gp, conv_b, score_w,
                                                         (unsigned int*)G, SW);
  coef_kernel<<<dim3(256), dim3(256), 0, stream>>>(ids, SW, coefs);
  gbst_main_kernel<<<dim3(256), dim3(512), 0, stream>>>(ids, G, coefs, conv_b, out);
}

// Round 18
// 48.984 us; speedup vs baseline: 1.9968x; 1.9968x over previous
//
#include <hip/hip_runtime.h>

#define VOCABN 256
#define DN 512
#define DSN 2
#define KN 5
#define BN 8
#define LN 8192
#define WN 12                     // window positions per block (multiple of lcm(2,3,4)=12)
#define NW12 ((LN + WN - 1) / WN) // 683 windows per batch
#define LOUTN (LN / DSN)          // 4096
#define NROWS (KN * VOCABN)       // 1280 G rows
#define ROWB (DN * 2)             // 1024 bytes per bf16 G row
#define KPLANE (VOCABN * ROWB)    // 262144 bytes per k-plane
#define ZOFFB (NROWS * ROWB)      // invalid-tap base: rows 1280+q*256 are zero rows
#define SBIAS_IDX (NROWS + 4 * VOCABN + 1)  // 2305
#define ISP 4                     // split over i: 4 chunks of 128

// Workspace layout (BYTES) — derived:
//   Gp : ISP*NROWS*DN*4 = 10,485,760 @ 0
//   G  : 2305*ROWB      =  2,360,320 @ 10,485,760
//   SW : 2306*4         =      9,224 @ 12,846,080
#define GP_BYTES ((size_t)ISP * NROWS * DN * 4)
#define G_OFF GP_BYTES
#define SW_OFF (G_OFF + (size_t)2305 * ROWB)

typedef float nf2 __attribute__((ext_vector_type(2)));  // clang vector for nontemporal store

__device__ inline unsigned short f2bf(float f) {  // RNE f32->bf16
  unsigned int x = __float_as_uint(f);
  return (unsigned short)((x + 0x7FFFu + ((x >> 16) & 1u)) >> 16);
}

// ---------------- kernel 1: build GEMM partials (round-7/11 verbatim) ----------------
__global__ __launch_bounds__(256) void gbuild_kernel(const float* __restrict__ emb,
                                                     const float* __restrict__ cw,
                                                     float* __restrict__ Gp) {
  const int bx = blockIdx.x;
  const int vt = bx & 3, ot = (bx >> 2) & 7;
  const int kq = bx >> 5;
  const int k = kq % 5, isp = kq / 5;
  const int v0 = vt * 64, o0 = ot * 64;
  const int tid = threadIdx.x;
  const int ox = tid & 15, vx = tid >> 4;
  const int c = tid & 31, rr = tid >> 5;  // stage: i-col 0..31, row-group 0..7
  __shared__ float se[32][68];  // [i][v]
  __shared__ float wt[32][68];  // [i][o]
  float acc[4][4] = {};
  for (int ic = 0; ic < 4; ++ic) {
    const int i0 = isp * 128 + ic * 32;
    __syncthreads();  // protect previous iter's reads
#pragma unroll
    for (int p = 0; p < 8; ++p) {
      const int q = p * 8 + rr;
      se[c][q] = emb[(size_t)(v0 + q) * DN + i0 + c];                  // coalesced rows
      wt[c][q] = cw[((size_t)(o0 + q) * DN + i0 + c) * KN + k];        // strided, L2-hot
    }
    __syncthreads();
#pragma unroll
    for (int i = 0; i < 32; ++i) {
      const float4 a = *(const float4*)&se[i][vx * 4];
      const float4 b = *(const float4*)&wt[i][ox * 4];
      acc[0][0] += a.x * b.x; acc[0][1] += a.x * b.y; acc[0][2] += a.x * b.z; acc[0][3] += a.x * b.w;
      acc[1][0] += a.y * b.x; acc[1][1] += a.y * b.y; acc[1][2] += a.y * b.z; acc[1][3] += a.y * b.w;
      acc[2][0] += a.z * b.x; acc[2][1] += a.z * b.y; acc[2][2] += a.z * b.z; acc[2][3] += a.z * b.w;
      acc[3][0] += a.w * b.x; acc[3][1] += a.w * b.y; acc[3][2] += a.w * b.z; acc[3][3] += a.w * b.w;
    }
  }
#pragma unroll
  for (int vi = 0; vi < 4; ++vi) {
    const int row = k * VOCABN + v0 + vx * 4 + vi;
    float4 f;
    f.x = acc[vi][0];
    f.y = acc[vi][1];
    f.z = acc[vi][2];
    f.w = acc[vi][3];
    *(float4*)(Gp + ((size_t)isp * NROWS + row) * DN + o0 + ox * 4) = f;
  }
}

// ---------------- kernel 2: merged reduce + score table (round-11 verbatim) ----------------
__global__ __launch_bounds__(256) void gswr_kernel(const float* __restrict__ Gp,
                                                   const float* __restrict__ conv_b,
                                                   const float* __restrict__ score_w,
                                                   unsigned int* __restrict__ G32,
                                                   float* __restrict__ SW) {
  const int r = blockIdx.x;
  const int tid = threadIdx.x;
  __shared__ float sred[4];
  if (r >= NROWS && r < NROWS + 5) {  // zero rows
    const int z = NROWS + (r - NROWS) * VOCABN;
    G32[(size_t)z * 256 + tid] = 0u;
    if (tid == 0) SW[z] = 0.f;
    return;
  }
  const float2 sw2 = *(const float2*)(score_w + tid * 2);
  float sdot;
  if (r == NROWS + 5) {  // sbias = conv_b . score_w
    const float2 cb2 = *(const float2*)(conv_b + tid * 2);
    sdot = cb2.x * sw2.x + cb2.y * sw2.y;
  } else {
    float x = 0.f, y = 0.f;
#pragma unroll
    for (int isp = 0; isp < ISP; ++isp) {
      const float2 p = *(const float2*)(Gp + ((size_t)isp * NROWS + r) * DN + tid * 2);
      x += p.x;
      y += p.y;
    }
    G32[(size_t)r * 256 + tid] = (unsigned)f2bf(x) | ((unsigned)f2bf(y) << 16);
    sdot = x * sw2.x + y * sw2.y;
  }
#pragma unroll
  for (int off = 32; off > 0; off >>= 1) sdot += __shfl_xor(sdot, off, 64);
  if ((tid & 63) == 0) sred[tid >> 6] = sdot;
  __syncthreads();
  if (tid == 0) {
    const float v = sred[0] + sred[1] + sred[2] + sred[3];
    if (r == NROWS + 5) SW[SBIAS_IDX] = v;
    else SW[r] = v;
  }
}

// ---------------- kernel 3: fused GBST main (round-11 verbatim — best measured) ---------
__global__ __launch_bounds__(256, 5) void gbst_main_kernel(const int* __restrict__ ids,
                                                           const unsigned short* __restrict__ G,
                                                           const float* __restrict__ SW,
                                                           const float* __restrict__ conv_b,
                                                           float* __restrict__ out) {
  const int blk = blockIdx.x;
  const int b = blk / NW12;
  const int w = blk % NW12;
  const int l0 = w * WN;
  const int tid = threadIdx.x;

  __shared__ float t_s[WN];
  __shared__ float4 wm_s[WN];

  // P0: block-uniform tap byte-offsets (compiler emits s_load + scalar ALU)
  int joff[WN + 4];
#pragma unroll
  for (int j = 0; j < WN + 4; ++j) {
    const int p = l0 + j - 2;
    const bool v = ((unsigned)p < (unsigned)LN);
    const int a = v ? (b * LN + p) : 0;
    const int id = ids[a];
    joff[j] = v ? (id * ROWB) : ZOFFB;
  }

  // P1: gathers (uint = 2 bf16 channels); scalar base + tid voffset
  const char* Gc = (const char*)G;
  float2 y[WN];
#pragma unroll
  for (int s = 0; s < WN; ++s) {
    float ax = 0.f, ay = 0.f;
#pragma unroll
    for (int kk = 0; kk < KN; ++kk) {
      const unsigned g = ((const unsigned*)(Gc + (joff[s + kk] + kk * KPLANE)))[tid];
      ax += __uint_as_float(g << 16);
      ay += __uint_as_float(g & 0xFFFF0000u);
    }
    y[s].x = ax;
    y[s].y = ay;
  }
  const float2 bias = *(const float2*)(conv_b + tid * 2);
#pragma unroll
  for (int s = 0; s < WN; ++s) {
    const bool valid = (l0 + s) < LN;  // block-uniform
    y[s].x = valid ? y[s].x + bias.x : 0.f;
    y[s].y = valid ? y[s].y + bias.y : 0.f;
  }

  // P2 (wave 0 only): scalar-loaded scores, then softmax
  if (tid < 64) {
    const float sbias = SW[SBIAS_IDX];
    float t[WN];
#pragma unroll
    for (int s = 0; s < WN; ++s) {
      float tv = sbias;
#pragma unroll
      for (int kk = 0; kk < KN; ++kk) tv += SW[(joff[s + kk] >> 10) + kk * VOCABN];
      t[s] = (l0 + s < LN) ? tv : 0.f;
    }
    if (tid == 0) {
#pragma unroll
      for (int s = 0; s < WN; ++s) t_s[s] = t[s];  // compile-time indices only
    }
    if (tid < WN && l0 + tid < LN) {
      const int ll = tid;
      float s1 = t_s[ll];
      int j2 = ll & ~1;
      float s2 = 0.5f * (t_s[j2] + t_s[j2 + 1]);
      int j3 = (ll / 3) * 3;
      float s3 = (1.f / 3.f) * (t_s[j3] + t_s[j3 + 1] + t_s[j3 + 2]);
      int j4 = ll & ~3;
      float s4 = 0.25f * (t_s[j4] + t_s[j4 + 1] + t_s[j4 + 2] + t_s[j4 + 3]);
      float mx = fmaxf(fmaxf(s1, s2), fmaxf(s3, s4));
      float e1 = __expf(s1 - mx), e2 = __expf(s2 - mx);
      float e3 = __expf(s3 - mx), e4 = __expf(s4 - mx);
      float inv = 1.f / (e1 + e2 + e3 + e4);
      wm_s[ll] = make_float4(e1 * inv, e2 * inv, e3 * inv, e4 * inv);
    }
  }

  // P3: pool sums (before barrier — waves 1-3 overlap wave 0's softmax)
  float2 S2[6], S3[4], S4[3];
#pragma unroll
  for (int j = 0; j < 6; ++j) {
    S2[j].x = y[2 * j].x + y[2 * j + 1].x;
    S2[j].y = y[2 * j].y + y[2 * j + 1].y;
  }
#pragma unroll
  for (int j = 0; j < 4; ++j) {
    S3[j].x = y[3 * j].x + y[3 * j + 1].x + y[3 * j + 2].x;
    S3[j].y = y[3 * j].y + y[3 * j + 1].y + y[3 * j + 2].y;
  }
#pragma unroll
  for (int j = 0; j < 3; ++j) {
    S4[j].x = S2[2 * j].x + S2[2 * j + 1].x;
    S4[j].y = S2[2 * j].y + S2[2 * j + 1].y;
  }
  __syncthreads();

  // P4: latent mix + final /2 downsample, nontemporal clang-vector stores
#pragma unroll
  for (int jo = 0; jo < WN / 2; ++jo) {
    const int orow = (l0 >> 1) + jo;
    if (orow < LOUTN) {
      float ax = 0.f, ay = 0.f;
#pragma unroll
      for (int dl = 0; dl < 2; ++dl) {
        const int ll = 2 * jo + dl;
        const float4 wv = wm_s[ll];
        const float c2 = wv.y * 0.5f;
        const float c3 = wv.z * (1.f / 3.f);
        const float c4 = wv.w * 0.25f;
        ax += wv.x * y[ll].x + c2 * S2[jo].x + c3 * S3[ll / 3].x + c4 * S4[jo >> 1].x;
        ay += wv.x * y[ll].y + c2 * S2[jo].y + c3 * S3[ll / 3].y + c4 * S4[jo >> 1].y;
      }
      nf2 o2;
      o2.x = 0.5f * ax;
      o2.y = 0.5f * ay;
      __builtin_nontemporal_store(o2, (nf2*)(out + ((size_t)b * LOUTN + orow) * DN + tid * 2));
    }
  }
}

extern "C" void kernel_launch(void* const* d_in, const int* in_sizes, int n_in,
                              void* d_out, int out_size, void* d_ws, size_t ws_size,
                              hipStream_t stream) {
  const int* ids = (const int*)d_in[0];
  const float* emb = (const float*)d_in[1];
  const float* conv_w = (const float*)d_in[2];
  const float* conv_b = (const float*)d_in[3];
  const float* score_w = (const float*)d_in[4];
  float* out = (float*)d_out;

  char* ws = (char*)d_ws;
  float* Gp = (float*)ws;                               // 10,485,760 B
  unsigned short* G = (unsigned short*)(ws + G_OFF);    // 2,360,320 B @ 10,485,760
  float* SW = (float*)(ws + SW_OFF);                    // 9,224 B @ 12,846,080

  gbuild_kernel<<<dim3(640), dim3(256), 0, stream>>>(emb, conv_w, Gp);
  gswr_kernel<<<dim3(NROWS + 6), dim3(256), 0, stream>>>(Gp, conv_b, score_w,
                                                         (unsigned int*)G, SW);
  gbst_main_kernel<<<dim3(BN * NW12), dim3(256), 0, stream>>>(ids, G, SW, conv_b, out);
}